// Round 5
// baseline (184.277 us; speedup 1.0000x reference)
//
#include <hip/hip_runtime.h>

#define VOCAB 100000
#define DIM 128
#define BATCH 65536
#define N_NEG 10

// 16 lanes/element, 4 elements/wave, 4 waves/block => 16 elements/block
#define BLOCKS (BATCH / 16)   // 4096

__device__ __forceinline__ float softplus_f(float x) {
    // log(1+exp(x)), stable
    return fmaxf(x, 0.0f) + log1pf(__expf(-fabsf(x)));
}

__device__ __forceinline__ float dot4(float4 a, float4 b) {
    return a.x * b.x + a.y * b.y + a.z * b.z + a.w * b.w;
}

__global__ void zero_out_kernel(float* out) { out[0] = 0.0f; }

__global__ __launch_bounds__(256, 4) void skipgram_loss_kernel(
    const int* __restrict__ pos_u,
    const int* __restrict__ pos_v,
    const int* __restrict__ neg_v,
    const float4* __restrict__ u_weight,   // VOCAB x 32 float4
    const float4* __restrict__ v_weight,   // VOCAB x 32 float4
    float* __restrict__ out)
{
    const int tid  = threadIdx.x;
    const int lane = tid & 63;
    const int wave = tid >> 6;      // 0..3
    const int sub  = lane & 15;     // 0..15 within the 16-lane group
    const int grp  = lane >> 4;     // 0..3: group within wave

    const int b = (blockIdx.x * 4 + wave) * 4 + grp;   // one batch element per group

    const int iu = pos_u[b];
    const int iv = pos_v[b];
    int idx[N_NEG];
    #pragma unroll
    for (int n = 0; n < N_NEG; ++n) idx[n] = neg_v[b * N_NEG + n];

    const float4* __restrict__ urow = u_weight + iu * 32 + sub;
    const float4* rows[N_NEG + 1];
    rows[0] = v_weight + iv * 32 + sub;
    #pragma unroll
    for (int n = 0; n < N_NEG; ++n) rows[n + 1] = v_weight + idx[n] * 32 + sub;

    // preload the full u row (2 chunks of 16 float4, 256B segments per group)
    float4 u0 = urow[0];
    float4 u1 = urow[16];

    float acc[N_NEG + 1];

    // chunk-major: per chunk, 11 independent gathers issued back-to-back
    #pragma unroll
    for (int j = 0; j <= N_NEG; ++j) {
        acc[j] = dot4(u0, rows[j][0]);
    }
    #pragma unroll
    for (int j = 0; j <= N_NEG; ++j) {
        acc[j] += dot4(u1, rows[j][16]);
    }

    // reduce the 11 partial dots across the 16-lane group (4 levels)
    #pragma unroll
    for (int m = 1; m < 16; m <<= 1) {
        #pragma unroll
        for (int j = 0; j <= N_NEG; ++j) acc[j] += __shfl_xor(acc[j], m, 64);
    }

    float s = fminf(fmaxf(acc[0], -10.0f), 10.0f);
    float loss = softplus_f(-s);              // -log_sigmoid(s)
    #pragma unroll
    for (int n = 0; n < N_NEG; ++n)
        loss -= softplus_f(acc[n + 1]);       // + log_sigmoid(-d) == -softplus(d)

    // Each 16-lane group holds its loss (uniform within the group). Butterfly
    // over masks 16,32 pairs lanes of DIFFERENT groups -> every lane ends with
    // the sum of the 4 distinct group losses, each counted exactly once.
    #pragma unroll
    for (int m = 16; m < 64; m <<= 1) loss += __shfl_xor(loss, m, 64);

    __shared__ float smem[4];
    if (lane == 0) smem[wave] = loss;
    __syncthreads();
    if (tid == 0) {
        atomicAdd(out, (smem[0] + smem[1] + smem[2] + smem[3]) * (1.0f / (float)BATCH));
    }
}

extern "C" void kernel_launch(void* const* d_in, const int* in_sizes, int n_in,
                              void* d_out, int out_size, void* d_ws, size_t ws_size,
                              hipStream_t stream) {
    const int*    pos_u    = (const int*)d_in[0];
    const int*    pos_v    = (const int*)d_in[1];
    const int*    neg_v    = (const int*)d_in[2];
    const float4* u_weight = (const float4*)d_in[3];
    const float4* v_weight = (const float4*)d_in[4];
    float* out = (float*)d_out;

    zero_out_kernel<<<1, 1, 0, stream>>>(out);
    skipgram_loss_kernel<<<BLOCKS, 256, 0, stream>>>(
        pos_u, pos_v, neg_v, u_weight, v_weight, out);
}

// Round 6
// 160.257 us; speedup vs baseline: 1.1499x; 1.1499x over previous
//
#include <hip/hip_runtime.h>

#define VOCAB 100000
#define DIM 128
#define BATCH 65536
#define N_NEG 10

// 8 lanes/element, 8 elements/wave, 4 waves/block => 32 elements/block
#define BLOCKS (BATCH / 32)   // 2048

__device__ __forceinline__ float dot4(float4 a, float4 b) {
    return a.x * b.x + a.y * b.y + a.z * b.z + a.w * b.w;
}

// softplus(x)/ln2 = max(y,0) + log2(1 + 2^(-|y|)),  y = x*log2(e)
// Uses native v_exp_f32 / v_log_f32 (base-2) — ~6 VALU ops, no ocml log1pf.
// Caller multiplies the accumulated sum by ln2 once.
__device__ __forceinline__ float softplus_log2(float x) {
    const float y = x * 1.44269504f;                       // log2(e)
    const float t = __builtin_amdgcn_exp2f(-fabsf(y));     // 2^(-|y|)
    return fmaxf(y, 0.0f) + __builtin_amdgcn_logf(1.0f + t); // log2(1+t)
}

__global__ void zero_out_kernel(float* out) { out[0] = 0.0f; }

__global__ __launch_bounds__(256) void skipgram_loss_kernel(
    const int* __restrict__ pos_u,
    const int* __restrict__ pos_v,
    const int* __restrict__ neg_v,
    const float4* __restrict__ u_weight,   // VOCAB x 32 float4
    const float4* __restrict__ v_weight,   // VOCAB x 32 float4
    float* __restrict__ out)
{
    const int tid  = threadIdx.x;
    const int lane = tid & 63;
    const int wave = tid >> 6;      // 0..3
    const int sub  = lane & 7;      // 0..7 within the 8-lane group
    const int grp  = lane >> 3;     // 0..7: group within wave

    const int b = (blockIdx.x * 4 + wave) * 8 + grp;   // one batch element per group

    const int iu = pos_u[b];
    const int iv = pos_v[b];

    // u row: 4 chunks; chunk c = float4s [c*8 .. c*8+7] -> each inst 128B-coalesced/group
    const float4* __restrict__ urow = u_weight + iu * 32;
    float4 u0 = urow[0 * 8 + sub];
    float4 u1 = urow[1 * 8 + sub];
    float4 u2 = urow[2 * 8 + sub];
    float4 u3 = urow[3 * 8 + sub];

    const float4* __restrict__ vrow = v_weight + iv * 32;
    float p = dot4(u0, vrow[0 * 8 + sub]) + dot4(u1, vrow[1 * 8 + sub])
            + dot4(u2, vrow[2 * 8 + sub]) + dot4(u3, vrow[3 * 8 + sub]);

    float nd[N_NEG];
    #pragma unroll
    for (int n = 0; n < N_NEG; ++n) {
        const int idx = neg_v[b * N_NEG + n];
        const float4* __restrict__ wrow = v_weight + idx * 32;
        nd[n] = dot4(u0, wrow[0 * 8 + sub]) + dot4(u1, wrow[1 * 8 + sub])
              + dot4(u2, wrow[2 * 8 + sub]) + dot4(u3, wrow[3 * 8 + sub]);
    }

    // reduce the 11 dots across the 8-lane group (3 levels)
    #pragma unroll
    for (int m = 1; m < 8; m <<= 1) {
        p += __shfl_xor(p, m, 64);
        #pragma unroll
        for (int n = 0; n < N_NEG; ++n) nd[n] += __shfl_xor(nd[n], m, 64);
    }

    float s = fminf(fmaxf(p, -10.0f), 10.0f);
    // loss/ln2 accumulated in log2 domain; single ×ln2 at the end
    float loss2 = softplus_log2(-s);             // -log_sigmoid(s) / ln2
    #pragma unroll
    for (int n = 0; n < N_NEG; ++n)
        loss2 -= softplus_log2(nd[n]);           // + log_sigmoid(-d)/ln2
    float loss = loss2 * 0.69314718f;

    // Each 8-lane group holds its loss (uniform within the group). Butterfly
    // over masks 8,16,32 pairs lanes of DIFFERENT groups -> every lane ends
    // with the sum of the 8 distinct group losses, each counted exactly once.
    #pragma unroll
    for (int m = 8; m < 64; m <<= 1) loss += __shfl_xor(loss, m, 64);

    __shared__ float smem[4];
    if (lane == 0) smem[wave] = loss;
    __syncthreads();
    if (tid == 0) {
        atomicAdd(out, (smem[0] + smem[1] + smem[2] + smem[3]) * (1.0f / (float)BATCH));
    }
}

extern "C" void kernel_launch(void* const* d_in, const int* in_sizes, int n_in,
                              void* d_out, int out_size, void* d_ws, size_t ws_size,
                              hipStream_t stream) {
    const int*    pos_u    = (const int*)d_in[0];
    const int*    pos_v    = (const int*)d_in[1];
    const int*    neg_v    = (const int*)d_in[2];
    const float4* u_weight = (const float4*)d_in[3];
    const float4* v_weight = (const float4*)d_in[4];
    float* out = (float*)d_out;

    zero_out_kernel<<<1, 1, 0, stream>>>(out);
    skipgram_loss_kernel<<<BLOCKS, 256, 0, stream>>>(
        pos_u, pos_v, neg_v, u_weight, v_weight, out);
}